// Round 7
// baseline (154.390 us; speedup 1.0000x reference)
//
#include <hip/hip_runtime.h>
#include <cstdint>
#include <cstddef>

// ---------------------------------------------------------------------------
// SelfAttention (b=4, C=64, 128x128) — MFMA bf16, round 7.
// Math as rounds 2-6 (no-max softmax, fast-exp2, pi-permuted Vpp/Wop).
// Round-7: k_qkv moved to MFMA (bf16 hi/lo split of x and W => fp32-grade
// conv, 3-MFMA products); k_attn/k_lsum rebuilt at 256thr +
// __launch_bounds__(256,4) so the 128-VGPR budget holds register prefetch
// (round-6's 52-VGPR kernels sank prefetch loads => exposed L2 latency).
// ---------------------------------------------------------------------------

#define LOG2E 1.44269504088896340736f
#define FE_A 8388608.0f        // 2^23
#define FE_B 1064993098.0f     // 127*2^23 - 360118 (fast exp2 bias)

typedef __attribute__((ext_vector_type(8)))  __bf16 bf8_t;
typedef __attribute__((ext_vector_type(16))) float  fx16;

__device__ __forceinline__ unsigned short f2bf(float f) {
  unsigned int u = __builtin_bit_cast(unsigned int, f);
  u += 0x7FFFu + ((u >> 16) & 1u);   // round-nearest-even
  return (unsigned short)(u >> 16);
}
__device__ __forceinline__ float bf2f(unsigned short h) {
  unsigned int u = ((unsigned int)h) << 16;
  return __builtin_bit_cast(float, u);
}
__device__ __forceinline__ unsigned int pk2(unsigned short lo, unsigned short hi) {
  return (unsigned int)lo | ((unsigned int)hi << 16);
}
// involution permutation on a 16-group: swap middle two quads
__device__ __forceinline__ int pi16(int s) {
  int m = (s >> 2) & 3;
  return (m == 1 || m == 2) ? (s ^ 12) : s;
}
__device__ __forceinline__ unsigned fe_u(float s) {
  return (unsigned)fmaf(s, FE_A, FE_B);
}
__device__ __forceinline__ float fe_f(float s) {
  return __builtin_bit_cast(float, fe_u(s));
}
__device__ __forceinline__ unsigned fe_pk(float s0, float s1) {
  return __builtin_amdgcn_perm(fe_u(s1), fe_u(s0), 0x07060302);
}

#define MFMA __builtin_amdgcn_mfma_f32_32x32x16_bf16

// ----------------------- K1: fused q/k/v via MFMA ---------------------------
// Blocks 0..255 = (b, rowpair T). Stage x[64c][256pos] -> LDS bf16 hi/lo
// planes, [pos][16 swizzled 16B chunks]. 8 waves: wave (Mt = wv>>2, cg = wv&3)
// computes D[32ch x 32pos] for both spatial rows (r=0/1) with 3-MFMA hi/lo
// products. Epilogue: q stores (Mt0), 2x2-pool via reg-max + shfl_xor(1),
// KpB (*LOG2E folded into Wk) + Vp stores. Block 256 packs Wo.
__global__ void __launch_bounds__(512) k_qkv(const float* __restrict__ x,
                                             const float* __restrict__ Wq,
                                             const float* __restrict__ Wk,
                                             const float* __restrict__ Wv,
                                             const float* __restrict__ Wo,
                                             unsigned short* __restrict__ Qp,
                                             unsigned short* __restrict__ KpB,
                                             float* __restrict__ Vp,
                                             unsigned short* __restrict__ Wop) {
  if (blockIdx.x == 256) {                         // Wo -> bf16, pi on c-cols
    for (int i = threadIdx.x; i < 2048; i += 512) {
      int c = i & 31;
      Wop[i] = f2bf(Wo[(i & ~31) | (c & 16) | pi16(c & 15)]);
    }
    return;
  }
  __shared__ unsigned int xs[256 * 64];            // 64 KB: [pos][16 chunks][4 dw]
  int t = threadIdx.x;
  int b = blockIdx.x >> 6, T = blockIdx.x & 63;
  {
    int pos = t & 255, cslot = t >> 8;
    const float* xb = x + (size_t)b * (64 * 16384) + T * 256 + pos;
    int sw = pos & 15;
    unsigned int* row = xs + pos * 64;
#pragma unroll
    for (int i = 0; i < 16; ++i) {
      int p = cslot * 16 + i;
      float g0 = xb[(size_t)(2 * p) * 16384];
      float g1 = xb[(size_t)(2 * p + 1) * 16384];
      unsigned short h0 = f2bf(g0), h1 = f2bf(g1);
      unsigned short l0 = f2bf(g0 - bf2f(h0)), l1 = f2bf(g1 - bf2f(h1));
      int q = p >> 2, d = p & 3;
      row[((q + sw) & 15) * 4 + d] = pk2(h0, h1);
      row[((q + 8 + sw) & 15) * 4 + d] = pk2(l0, l1);
    }
  }
  // per-wave A-fragments (weights hi/lo), from global W (tiny, L2-hot)
  int wv = t >> 6, lane = t & 63;
  int cg = wv & 3, Mt = wv >> 2;
  int m = lane & 31, h = lane >> 5;
  const float* wrow;
  float scale = 1.0f;
  bool zero = false;
  if (Mt == 0) {
    if (m < 8) wrow = Wq + m * 64;
    else if (m < 16) { wrow = Wk + (m - 8) * 64; scale = LOG2E; }
    else wrow = Wv + (m - 16) * 64;
  } else {
    if (m < 16) wrow = Wv + (m + 16) * 64;
    else { wrow = Wq; zero = true; }
  }
  bf8_t Ahi[4], Alo[4];
#pragma unroll
  for (int kk = 0; kk < 4; ++kk) {
    unsigned short hi8[8], lo8[8];
#pragma unroll
    for (int j = 0; j < 8; ++j) {
      float w = zero ? 0.f : wrow[kk * 16 + h * 8 + j] * scale;
      unsigned short wh = f2bf(w);
      hi8[j] = wh;
      lo8[j] = f2bf(w - bf2f(wh));
    }
    uint4 uh, ul;
    uh.x = pk2(hi8[0], hi8[1]); uh.y = pk2(hi8[2], hi8[3]);
    uh.z = pk2(hi8[4], hi8[5]); uh.w = pk2(hi8[6], hi8[7]);
    ul.x = pk2(lo8[0], lo8[1]); ul.y = pk2(lo8[2], lo8[3]);
    ul.z = pk2(lo8[4], lo8[5]); ul.w = pk2(lo8[6], lo8[7]);
    Ahi[kk] = __builtin_bit_cast(bf8_t, uh);
    Alo[kk] = __builtin_bit_cast(bf8_t, ul);
  }
  __syncthreads();
  fx16 z;
#pragma unroll
  for (int i = 0; i < 16; ++i) z[i] = 0.f;
  fx16 D0 = z, D1 = z;
#pragma unroll
  for (int r = 0; r < 2; ++r) {
    fx16 acc = z;
    int pos = cg * 32 + r * 128 + (lane & 31);
    const unsigned int* row = xs + pos * 64;
    int sw = pos & 15;
#pragma unroll
    for (int kk = 0; kk < 4; ++kk) {
      int q = 2 * kk + h;
      bf8_t Bh = *reinterpret_cast<const bf8_t*>(&row[((q + sw) & 15) * 4]);
      bf8_t Bl = *reinterpret_cast<const bf8_t*>(&row[((q + 8 + sw) & 15) * 4]);
      acc = MFMA(Ahi[kk], Bh, acc, 0, 0, 0);
      acc = MFMA(Ahi[kk], Bl, acc, 0, 0, 0);
      acc = MFMA(Alo[kk], Bh, acc, 0, 0, 0);
    }
    if (r == 0) D0 = acc; else D1 = acc;
  }
  uint2 z2; z2.x = z2.y = 0u;
  if (Mt == 0) {                                   // q rows 0-7 (regs 0-3 x h)
#pragma unroll
    for (int r = 0; r < 2; ++r) {
      const fx16& D = r ? D1 : D0;
      int gpos = T * 256 + r * 128 + cg * 32 + (lane & 31);
      unsigned short* qd = Qp + ((size_t)b * 16384 + gpos) * 16;
      uint2 qa;
      qa.x = pk2(f2bf(D[0]), f2bf(D[1]));
      qa.y = pk2(f2bf(D[2]), f2bf(D[3]));
      *reinterpret_cast<uint2*>(qd + h * 4) = qa;
      *reinterpret_cast<uint2*>(qd + 8 + h * 4) = z2;
    }
  }
  float pm[16];                                    // 2x2 maxpool
#pragma unroll
  for (int r0 = 0; r0 < 16; ++r0) {
    float a = fmaxf(D0[r0], __shfl_xor(D0[r0], 1));
    float bb = fmaxf(D1[r0], __shfl_xor(D1[r0], 1));
    pm[r0] = fmaxf(a, bb);
  }
  if ((lane & 1) == 0) {
    size_t idx = (size_t)b * 4096 + T * 64 + cg * 16 + ((lane & 31) >> 1);
    float* vd = Vp + idx * 32;
    if (Mt == 0) {
      // k-ch: regs 4-7 (rows 8-15, pre-scaled by LOG2E); v0-15: regs 8-15
      uint2 kw;
      kw.x = pk2(f2bf(pm[4]), f2bf(pm[5]));
      kw.y = pk2(f2bf(pm[6]), f2bf(pm[7]));
      *reinterpret_cast<uint2*>(KpB + idx * 16 + h * 4) = kw;
      *reinterpret_cast<float4*>(vd + h * 4) = make_float4(pm[8], pm[9], pm[10], pm[11]);
      *reinterpret_cast<float4*>(vd + 8 + h * 4) = make_float4(pm[12], pm[13], pm[14], pm[15]);
    } else {
      // zero-pad KpB halves 8-15; v16-31: regs 0-7
      *reinterpret_cast<uint2*>(KpB + idx * 16 + 8 + h * 4) = z2;
      *reinterpret_cast<float4*>(vd + 16 + h * 4) = make_float4(pm[0], pm[1], pm[2], pm[3]);
      *reinterpret_cast<float4*>(vd + 24 + h * 4) = make_float4(pm[4], pm[5], pm[6], pm[7]);
    }
  }
}

// --------------------- K2: partial l = sum exp2(S2) -------------------------
// grid 1024 = (b4 x fgpair64 x kq4), 256 thr, 128-VGPR budget. FB=2: one Q
// fragment feeds 2 MFMAs. Waves split the k-quarter 4-ways (32 chunks each).
__global__ void __launch_bounds__(256, 4) k_lsum(const unsigned short* __restrict__ Qp,
                                                 const unsigned short* __restrict__ KpB,
                                                 float* __restrict__ Lpart) {
  int b = blockIdx.x >> 8, r = blockIdx.x & 255;
  int g = r >> 2, kq = r & 3;
  int wv = threadIdx.x >> 6, lane = threadIdx.x & 63;
  int half = lane >> 5, l31 = lane & 31;
  const unsigned short* kb =
      KpB + ((size_t)(b * 4096 + g * 64 + l31)) * 16 + half * 8;
  bf8_t A0 = *reinterpret_cast<const bf8_t*>(kb);
  bf8_t A1 = *reinterpret_cast<const bf8_t*>(kb + 32 * 16);
  const unsigned short* qbase = Qp + ((size_t)b * 16384) * 16 + half * 8;
  fx16 z;
#pragma unroll
  for (int i = 0; i < 16; ++i) z[i] = 0.f;
  float l[32];
#pragma unroll
  for (int i = 0; i < 32; ++i) l[i] = 0.f;
  int t0 = kq * 128 + wv * 32;
  bf8_t B = *reinterpret_cast<const bf8_t*>(qbase + (size_t)(t0 * 32 + l31) * 16);
  for (int i = 0; i < 32; ++i) {
    int tn = t0 + ((i + 1) & 31);
    bf8_t nB = *reinterpret_cast<const bf8_t*>(qbase + (size_t)(tn * 32 + l31) * 16);
    fx16 s0 = MFMA(A0, B, z, 0, 0, 0);
    fx16 s1 = MFMA(A1, B, z, 0, 0, 0);
#pragma unroll
    for (int r0 = 0; r0 < 16; ++r0) l[r0] += fe_f(s0[r0]);
#pragma unroll
    for (int r0 = 0; r0 < 16; ++r0) l[16 + r0] += fe_f(s1[r0]);
    B = nB;
  }
#pragma unroll
  for (int r0 = 0; r0 < 32; ++r0)
    for (int d = 1; d < 32; d <<= 1) l[r0] += __shfl_xor(l[r0], d);
  __shared__ float sl[4][2][32];
  if (l31 == 0) {
#pragma unroll
    for (int r0 = 0; r0 < 16; ++r0) {
      int row = (r0 & 3) + 8 * (r0 >> 2) + 4 * half;
      sl[wv][0][row] = l[r0];
      sl[wv][1][row] = l[16 + r0];
    }
  }
  __syncthreads();
  if (threadIdx.x < 64) {
    int fgi = threadIdx.x >> 5, row = threadIdx.x & 31;
    float L = sl[0][fgi][row] + sl[1][fgi][row] + sl[2][fgi][row] + sl[3][fgi][row];
    Lpart[(size_t)kq * 16384 + b * 4096 + g * 64 + fgi * 32 + row] = L;
  }
}

// ------------------------------ K3: pack -----------------------------------
// Vpp[b][c][f'] bf16 = Vp[b][pi(f)][c] / sum_kq Lpart[kq][pi(f)].
__global__ void __launch_bounds__(256) k_pack(const float* __restrict__ Vp,
                                              const float* __restrict__ Lpart,
                                              unsigned short* __restrict__ Vpp) {
  int b = blockIdx.x >> 4, f0 = (blockIdx.x & 15) * 256;
  __shared__ unsigned short Tt[32][264];           // +8 pad, rows 16B-aligned
  int t = threadIdx.x;
  size_t li = (size_t)b * 4096 + f0 + t;
  float L = Lpart[li] + Lpart[li + 16384] + Lpart[li + 32768] + Lpart[li + 49152];
  float rl = 1.0f / L;
  const float* vp = Vp + li * 32;
  int fl = (t & ~15) | pi16(t & 15);               // destination column
  for (int c = 0; c < 32; ++c) Tt[c][fl] = f2bf(vp[c] * rl);
  __syncthreads();
  for (int u = t; u < 1024; u += 256) {            // 32 rows x 32 uint4
    int row = u >> 5, e0 = (u & 31) * 8;
    uint4 val = *reinterpret_cast<const uint4*>(&Tt[row][e0]);
    *reinterpret_cast<uint4*>(Vpp + ((size_t)b * 32 + row) * 4096 + f0 + e0) = val;
  }
}

// ------------------------- K4: attention + project --------------------------
// 256 thr (4 waves) per 64-k pair, __launch_bounds__(256,4) => 128-VGPR
// budget holds the 1-deep K/V register prefetch. Waves split f 4-ways
// (32 chunks), KB=2. All 4 waves deposit accs; waves 0/1 do the kt=wv
// epilogue (both o-tiles) with early x residual prefetch.
__global__ void __launch_bounds__(256, 4) k_attn(const unsigned short* __restrict__ Qp,
                                                 const unsigned short* __restrict__ KpB,
                                                 const unsigned short* __restrict__ Vpp,
                                                 const unsigned short* __restrict__ Wop,
                                                 const float* __restrict__ x,
                                                 const float* __restrict__ gamma,
                                                 float* __restrict__ out) {
  int b = blockIdx.x >> 8, kp = blockIdx.x & 255;
  int wv = threadIdx.x >> 6, lane = threadIdx.x & 63;
  int half = lane >> 5, l31 = lane & 31;
  int kbase = kp * 64;
  const unsigned short* qb = Qp + ((size_t)b * 16384 + kbase + l31) * 16 + half * 8;
  bf8_t Bq0 = *reinterpret_cast<const bf8_t*>(qb);
  bf8_t Bq1 = *reinterpret_cast<const bf8_t*>(qb + 32 * 16);
  fx16 z;
#pragma unroll
  for (int i = 0; i < 16; ++i) z[i] = 0.f;
  fx16 acc0 = z, acc1 = z;
  const unsigned short* kpB = KpB + ((size_t)b * 4096 + l31) * 16 + half * 8;
  const unsigned short* vpB = Vpp + ((size_t)(b * 32 + l31)) * 4096 + half * 8;
  int c0 = wv * 32;                                // wave's first f-chunk
  int f0 = c0 * 32;
  bf8_t Ak  = *reinterpret_cast<const bf8_t*>(kpB + (size_t)f0 * 16);
  bf8_t Av0 = *reinterpret_cast<const bf8_t*>(vpB + f0);
  bf8_t Av1 = *reinterpret_cast<const bf8_t*>(vpB + f0 + 16);
  for (int fc = 0; fc < 32; ++fc) {
    int f1 = (c0 + ((fc + 1) & 31)) * 32;          // wraps within wave's range
    bf8_t nAk  = *reinterpret_cast<const bf8_t*>(kpB + (size_t)f1 * 16);
    bf8_t nAv0 = *reinterpret_cast<const bf8_t*>(vpB + f1);
    bf8_t nAv1 = *reinterpret_cast<const bf8_t*>(vpB + f1 + 16);
    fx16 s0 = MFMA(Ak, Bq0, z, 0, 0, 0);
    fx16 s1 = MFMA(Ak, Bq1, z, 0, 0, 0);
    uint4 u00, u01, u10, u11;
    u00.x = fe_pk(s0[0], s0[1]);   u00.y = fe_pk(s0[2], s0[3]);
    u00.z = fe_pk(s0[4], s0[5]);   u00.w = fe_pk(s0[6], s0[7]);
    u01.x = fe_pk(s0[8], s0[9]);   u01.y = fe_pk(s0[10], s0[11]);
    u01.z = fe_pk(s0[12], s0[13]); u01.w = fe_pk(s0[14], s0[15]);
    u10.x = fe_pk(s1[0], s1[1]);   u10.y = fe_pk(s1[2], s1[3]);
    u10.z = fe_pk(s1[4], s1[5]);   u10.w = fe_pk(s1[6], s1[7]);
    u11.x = fe_pk(s1[8], s1[9]);   u11.y = fe_pk(s1[10], s1[11]);
    u11.z = fe_pk(s1[12], s1[13]); u11.w = fe_pk(s1[14], s1[15]);
    bf8_t P00 = __builtin_bit_cast(bf8_t, u00);
    bf8_t P01 = __builtin_bit_cast(bf8_t, u01);
    bf8_t P10 = __builtin_bit_cast(bf8_t, u10);
    bf8_t P11 = __builtin_bit_cast(bf8_t, u11);
    acc0 = MFMA(Av0, P00, acc0, 0, 0, 0);
    acc1 = MFMA(Av0, P10, acc1, 0, 0, 0);
    acc0 = MFMA(Av1, P01, acc0, 0, 0, 0);
    acc1 = MFMA(Av1, P11, acc1, 0, 0, 0);
    Ak = nAk; Av0 = nAv0; Av1 = nAv1;
  }
  __shared__ float sacc[4][2][4][64][4];           // 32 KB
#pragma unroll
  for (int j4 = 0; j4 < 4; ++j4) {
    *reinterpret_cast<float4*>(&sacc[wv][0][j4][lane][0]) =
        make_float4(acc0[4 * j4], acc0[4 * j4 + 1], acc0[4 * j4 + 2], acc0[4 * j4 + 3]);
    *reinterpret_cast<float4*>(&sacc[wv][1][j4][lane][0]) =
        make_float4(acc1[4 * j4], acc1[4 * j4 + 1], acc1[4 * j4 + 2], acc1[4 * j4 + 3]);
  }
  __syncthreads();
  if (wv >= 2) return;
  int kt = wv;
  int k = kbase + kt * 32 + l31;
  const float* xp = x + (size_t)b * 64 * 16384 + k;
  float xv0[16], xv1[16];                          // early residual prefetch
#pragma unroll
  for (int r0 = 0; r0 < 16; ++r0) {
    int row = (r0 & 3) + 8 * (r0 >> 2) + 4 * half;
    xv0[r0] = xp[(size_t)row * 16384];
    xv1[r0] = xp[(size_t)(row + 32) * 16384];
  }
  fx16 tot;
#pragma unroll
  for (int j4 = 0; j4 < 4; ++j4) {
    float4 a0 = *reinterpret_cast<const float4*>(&sacc[0][kt][j4][lane][0]);
    float4 a1 = *reinterpret_cast<const float4*>(&sacc[1][kt][j4][lane][0]);
    float4 a2 = *reinterpret_cast<const float4*>(&sacc[2][kt][j4][lane][0]);
    float4 a3 = *reinterpret_cast<const float4*>(&sacc[3][kt][j4][lane][0]);
    tot[4 * j4]     = (a0.x + a1.x) + (a2.x + a3.x);
    tot[4 * j4 + 1] = (a0.y + a1.y) + (a2.y + a3.y);
    tot[4 * j4 + 2] = (a0.z + a1.z) + (a2.z + a3.z);
    tot[4 * j4 + 3] = (a0.w + a1.w) + (a2.w + a3.w);
  }
  bf8_t Ob0, Ob1;
#pragma unroll
  for (int j = 0; j < 8; ++j) { Ob0[j] = (__bf16)tot[j]; Ob1[j] = (__bf16)tot[8 + j]; }
  const unsigned short* wb = Wop + l31 * 32 + half * 8;
  bf8_t Aw00 = *reinterpret_cast<const bf8_t*>(wb);
  bf8_t Aw01 = *reinterpret_cast<const bf8_t*>(wb + 16);
  bf8_t Aw10 = *reinterpret_cast<const bf8_t*>(wb + 1024);
  bf8_t Aw11 = *reinterpret_cast<const bf8_t*>(wb + 1024 + 16);
  fx16 y0 = MFMA(Aw00, Ob0, z, 0, 0, 0);
  y0 = MFMA(Aw01, Ob1, y0, 0, 0, 0);
  fx16 y1 = MFMA(Aw10, Ob0, z, 0, 0, 0);
  y1 = MFMA(Aw11, Ob1, y1, 0, 0, 0);
  float g = gamma[0];
  float* op = out + (size_t)b * 64 * 16384 + k;
#pragma unroll
  for (int r0 = 0; r0 < 16; ++r0) {
    int row = (r0 & 3) + 8 * (r0 >> 2) + 4 * half;
    op[(size_t)row * 16384]        = fmaf(g, y0[r0], xv0[r0]);
    op[(size_t)(row + 32) * 16384] = fmaf(g, y1[r0], xv1[r0]);
  }
}

// ---------------------------------------------------------------------------
extern "C" void kernel_launch(void* const* d_in, const int* in_sizes, int n_in,
                              void* d_out, int out_size, void* d_ws, size_t ws_size,
                              hipStream_t stream) {
  const float* x     = (const float*)d_in[0];
  const float* Wq    = (const float*)d_in[1];
  const float* Wk    = (const float*)d_in[2];
  const float* Wv    = (const float*)d_in[3];
  const float* Wo    = (const float*)d_in[4];
  const float* gamma = (const float*)d_in[5];
  float* out = (float*)d_out;
  char* ws = (char*)d_ws;
  // workspace layout (bytes)
  unsigned short* Qp    = (unsigned short*)(ws + 0);        // 2 MB
  unsigned short* KpB   = (unsigned short*)(ws + 2097152);  // 512 KB
  float*          Vp    = (float*)(ws + 2621440);           // 2 MB
  unsigned short* Vpp   = (unsigned short*)(ws + 4718592);  // 1 MB
  float*          Lpart = (float*)(ws + 5767168);           // 256 KB (4 planes)
  unsigned short* Wop   = (unsigned short*)(ws + 6029312);  // 4 KB

  k_qkv <<<dim3(257),  dim3(512), 0, stream>>>(x, Wq, Wk, Wv, Wo, Qp, KpB, Vp, Wop);
  k_lsum<<<dim3(1024), dim3(256), 0, stream>>>(Qp, KpB, Lpart);
  k_pack<<<dim3(64),   dim3(256), 0, stream>>>(Vp, Lpart, Vpp);
  k_attn<<<dim3(1024), dim3(256), 0, stream>>>(Qp, KpB, Vpp, Wop, x, gamma, out);
}